// Round 1
// baseline (1205.711 us; speedup 1.0000x reference)
//
#include <hip/hip_runtime.h>
#include <hip/hip_bf16.h>

// Sizes (compile-time)
#define B_ 16
#define N_ 1024
#define CIN 24
#define EMB_ 64
#define HID_ 32
#define OUT_ 12
#define BH_ 32            // B*HEADS
#define RSQRT12 0.28867513459481287f

// ---------------- workspace layout (floats) ----------------
#define OFF_Q      0              // 393216
#define OFF_K      393216         // 393216
#define OFF_M      786432         // 32768
#define OFF_ZI     819200         // 32768
#define OFF_DEG    851968         // 2048 (deg_out[1024], deg_in[1024])
#define OFF_T1O    854016         // 393216
#define OFF_T1I    1247232        // 393216
#define OFF_SPAT   1640448        // 1048576
#define OFF_TEMP   2689024        // 1048576
#define OFF_WFT    3737600        // 12288  (128 x 96, transposed fold of Wih@We)
#define OFF_BF     3749888        // 128
#define OFF_XP     3750016        // 1572864
#define OFF_HS     5322880        // 524288
// total 5847168 floats = ~22.3 MB

// ---------------- q/k projection ----------------
__global__ __launch_bounds__(256) void qk_kernel(
    const float* __restrict__ x, const float* __restrict__ Wq, const float* __restrict__ bq,
    const float* __restrict__ Wk, const float* __restrict__ bk,
    float* __restrict__ q, float* __restrict__ k) {
  int t = blockIdx.x * 256 + threadIdx.x;
  if (t >= B_ * N_ * CIN) return;
  int bi = t / CIN, c = t % CIN;
  int b = bi >> 10, i = bi & (N_ - 1);
  const float* xr = x + bi * CIN;
  float aq = bq[c], ak = bk[c];
#pragma unroll
  for (int d = 0; d < CIN; d++) {
    float xv = xr[d];
    aq += xv * Wq[c * CIN + d];
    ak += xv * Wk[c * CIN + d];
  }
  int h = c / 12, cc = c - h * 12;
  int qi = ((b * 2 + h) * N_ + i) * 12 + cc;
  q[qi] = aq;
  k[qi] = ak;
}

// ---------------- per-row online softmax stats (max, 1/sum) ----------------
__global__ __launch_bounds__(256) void row_lse_kernel(
    const float* __restrict__ q, const float* __restrict__ k,
    float* __restrict__ mrow, float* __restrict__ zinv) {
  __shared__ float ks[N_ * 12];         // 48KB: all K rows for this (b,h)
  __shared__ float pm[4][64];
  __shared__ float pz[4][64];
  int bh = blockIdx.x >> 4;             // 0..31
  int rg = blockIdx.x & 15;             // row group of 64
  const float4* k4 = (const float4*)(k + bh * N_ * 12);
  float4* ks4 = (float4*)ks;
  for (int i = threadIdx.x; i < N_ * 3; i += 256) ks4[i] = k4[i];
  int wave = threadIdx.x >> 6, lane = threadIdx.x & 63;
  int row = rg * 64 + lane;
  float qr[12];
  const float* qp = q + (bh * N_ + row) * 12;
#pragma unroll
  for (int c = 0; c < 12; c++) qr[c] = qp[c];
  __syncthreads();
  float mloc = -1e30f, zloc = 0.f;
  for (int j = wave * 256; j < wave * 256 + 256; j++) {
    const float* kj = ks + j * 12;
    float s = 0.f;
#pragma unroll
    for (int c = 0; c < 12; c++) s += qr[c] * kj[c];
    s *= RSQRT12;
    float mn = fmaxf(mloc, s);
    zloc = zloc * __expf(mloc - mn) + __expf(s - mn);
    mloc = mn;
  }
  pm[wave][lane] = mloc;
  pz[wave][lane] = zloc;
  __syncthreads();
  if (threadIdx.x < 64) {
    int r = rg * 64 + threadIdx.x;
    float M = fmaxf(fmaxf(pm[0][threadIdx.x], pm[1][threadIdx.x]),
                    fmaxf(pm[2][threadIdx.x], pm[3][threadIdx.x]));
    float Z = pz[0][threadIdx.x] * __expf(pm[0][threadIdx.x] - M) +
              pz[1][threadIdx.x] * __expf(pm[1][threadIdx.x] - M) +
              pz[2][threadIdx.x] * __expf(pm[2][threadIdx.x] - M) +
              pz[3][threadIdx.x] * __expf(pm[3][threadIdx.x] - M);
    mrow[bh * N_ + r] = M;
    zinv[bh * N_ + r] = 1.f / Z;
  }
}

// ---------------- per-edge attention score -> ew -> degree atomics ----------------
__global__ __launch_bounds__(256) void edge_stats_kernel(
    const float* __restrict__ q, const float* __restrict__ k,
    const float* __restrict__ mrow, const float* __restrict__ zinv,
    const int* __restrict__ ei, const float* __restrict__ ewt, int E,
    float* __restrict__ deg) {
  int e = blockIdx.x * 256 + threadIdx.x;
  if (e >= E) return;
  int src = ei[e], dst = ei[E + e];
  float acc = 0.f;
  for (int bh = 0; bh < BH_; bh++) {
    const float* qp = q + (bh * N_ + src) * 12;
    const float* kp = k + (bh * N_ + dst) * 12;
    float s = 0.f;
#pragma unroll
    for (int c = 0; c < 12; c++) s += qp[c] * kp[c];
    s *= RSQRT12;
    acc += __expf(s - mrow[bh * N_ + src]) * zinv[bh * N_ + src];
  }
  float w = 25.f * ewt[e] * (acc * (1.f / 32.f));
  atomicAdd(&deg[src], w);
  atomicAdd(&deg[N_ + dst], w);
}

__global__ void inv_deg_kernel(float* deg) {
  int t = blockIdx.x * 256 + threadIdx.x;
  if (t < 2 * N_) deg[t] = 1.f / deg[t];
}

// ---------------- scatter messages ----------------
__global__ __launch_bounds__(256) void scatter_kernel(
    const float* __restrict__ x, const int* __restrict__ ei,
    const float* __restrict__ deginv, int E,
    float* __restrict__ t1o, float* __restrict__ t1i) {
  int t = blockIdx.x * 256 + threadIdx.x;
  if (t >= E * CIN) return;
  int e = t / CIN, c = t % CIN;
  int src = ei[e], dst = ei[E + e];
  float ivo = deginv[src], ivi = deginv[N_ + dst];
#pragma unroll
  for (int b = 0; b < B_; b++) {
    atomicAdd(&t1o[(b * N_ + dst) * CIN + c], x[(b * N_ + src) * CIN + c] * ivo);
    atomicAdd(&t1i[(b * N_ + src) * CIN + c], x[(b * N_ + dst) * CIN + c] * ivi);
  }
}

// ---------------- spatial = relu(x@(W00+W10) + t1o@W01 + t1i@W11 + bd) ----------------
__global__ __launch_bounds__(256) void spatial_kernel(
    const float* __restrict__ x, const float* __restrict__ t1o, const float* __restrict__ t1i,
    const float* __restrict__ Wd, const float* __restrict__ bd, float* __restrict__ sp) {
  int t = blockIdx.x * 256 + threadIdx.x;
  if (t >= B_ * N_ * EMB_) return;
  int o = t & 63, bi = t >> 6;
  const float* xr = x + bi * CIN;
  const float* ar = t1o + bi * CIN;
  const float* br = t1i + bi * CIN;
  float acc = bd[o];
#pragma unroll
  for (int d = 0; d < CIN; d++) {
    acc += xr[d] * (Wd[d * 64 + o] + Wd[3072 + d * 64 + o]);  // Wd[0,0] + Wd[1,0]
    acc += ar[d] * Wd[1536 + d * 64 + o];                     // Wd[0,1]
    acc += br[d] * Wd[4608 + d * 64 + o];                     // Wd[1,1]
  }
  sp[t] = fmaxf(acc, 0.f);
}

// ---------------- fused TCN (2 residual blocks) over node axis ----------------
#define TW 70  // 64 + halo 6
__global__ __launch_bounds__(512) void tcn_kernel(
    const float* __restrict__ x,
    const float* __restrict__ c1w0, const float* __restrict__ c1b0,
    const float* __restrict__ c2w0, const float* __restrict__ c2b0,
    const float* __restrict__ dw0, const float* __restrict__ db0,
    const float* __restrict__ c1w1, const float* __restrict__ c1b1,
    const float* __restrict__ c2w1, const float* __restrict__ c2b1,
    float* __restrict__ temporal) {
  __shared__ float xs[CIN * TW];
  __shared__ float bufA[64 * TW];
  __shared__ float bufB[64 * TW];
  int b = blockIdx.x >> 4;
  int t0 = (blockIdx.x & 15) << 6;
  int tid = threadIdx.x;
  for (int i = tid; i < CIN * TW; i += 512) {
    int ln = i / CIN, c = i % CIN;
    int n = t0 - 6 + ln;
    xs[c * TW + ln] = (n >= 0) ? x[(b * N_ + n) * CIN + c] : 0.f;
  }
  __syncthreads();
  // L1: o1 = relu(conv(x, c1w0, d=1)); valid ln>=1; mask n<0 to 0 (causal pad semantics)
  for (int i = tid; i < 64 * (TW - 1); i += 512) {
    int co = i / (TW - 1), ln = 1 + i % (TW - 1);
    const float* w = c1w0 + co * 48;
    float acc = c1b0[co];
#pragma unroll
    for (int ci = 0; ci < CIN; ci++)
      acc += w[ci * 2] * xs[ci * TW + ln - 1] + w[ci * 2 + 1] * xs[ci * TW + ln];
    int n = t0 - 6 + ln;
    bufB[co * TW + ln] = (n >= 0) ? fmaxf(acc, 0.f) : 0.f;
  }
  __syncthreads();
  // L2 + downsample: h1 = relu(relu(conv(o1,c2w0)) + (x@dw0+db0)); valid ln>=2
  for (int i = tid; i < 64 * (TW - 2); i += 512) {
    int co = i / (TW - 2), ln = 2 + i % (TW - 2);
    const float* w = c2w0 + co * 128;
    float acc = c2b0[co];
#pragma unroll
    for (int ci = 0; ci < 64; ci++)
      acc += w[ci * 2] * bufB[ci * TW + ln - 1] + w[ci * 2 + 1] * bufB[ci * TW + ln];
    const float* wd = dw0 + co * CIN;
    float ds = db0[co];
#pragma unroll
    for (int ci = 0; ci < CIN; ci++) ds += wd[ci] * xs[ci * TW + ln];
    float v = fmaxf(fmaxf(acc, 0.f) + ds, 0.f);
    int n = t0 - 6 + ln;
    bufA[co * TW + ln] = (n >= 0) ? v : 0.f;
  }
  __syncthreads();
  // L3: o3 = relu(conv(h1, c1w1, d=2)); valid ln>=4
  for (int i = tid; i < 64 * (TW - 4); i += 512) {
    int co = i / (TW - 4), ln = 4 + i % (TW - 4);
    const float* w = c1w1 + co * 128;
    float acc = c1b1[co];
#pragma unroll
    for (int ci = 0; ci < 64; ci++)
      acc += w[ci * 2] * bufA[ci * TW + ln - 2] + w[ci * 2 + 1] * bufA[ci * TW + ln];
    int n = t0 - 6 + ln;
    bufB[co * TW + ln] = (n >= 0) ? fmaxf(acc, 0.f) : 0.f;
  }
  __syncthreads();
  // L4 + residual: out = relu(relu(conv(o3,c2w1,d=2)) + h1); ln in [6,70)
  for (int i = tid; i < 64 * 64; i += 512) {
    int co = i >> 6, ln = 6 + (i & 63);
    const float* w = c2w1 + co * 128;
    float acc = c2b1[co];
#pragma unroll
    for (int ci = 0; ci < 64; ci++)
      acc += w[ci * 2] * bufB[ci * TW + ln - 2] + w[ci * 2 + 1] * bufB[ci * TW + ln];
    float v = fmaxf(fmaxf(acc, 0.f) + bufA[co * TW + ln], 0.f);
    temporal[(b * N_ + t0 + ln - 6) * 64 + co] = v;
  }
}

// ---------------- fold Wih@We (and bias) so xp comes straight from [temporal|spatial] ----------------
__global__ void wfold_kernel(const float* __restrict__ We, const float* __restrict__ be,
                             const float* __restrict__ Wih, const float* __restrict__ bih,
                             float* __restrict__ WfT, float* __restrict__ bf) {
  int t = blockIdx.x * 256 + threadIdx.x;
  if (t < 128 * 96) {
    int o = t % 96, c = t / 96;
    float acc = 0.f;
#pragma unroll
    for (int e = 0; e < 12; e++) acc += Wih[o * 12 + e] * We[e * 128 + c];
    WfT[c * 96 + o] = acc;  // transposed: [c][o]
  }
  if (t < 96) {
    float acc = bih[t];
#pragma unroll
    for (int e = 0; e < 12; e++) acc += Wih[t * 12 + e] * be[e];
    bf[t] = acc;
  }
}

// ---------------- xp = [temporal|spatial] @ WfT + bf ----------------
__global__ __launch_bounds__(256) void xp_kernel(
    const float* __restrict__ temporal, const float* __restrict__ spatial,
    const float* __restrict__ WfT, const float* __restrict__ bf, float* __restrict__ xp) {
  int t = blockIdx.x * 256 + threadIdx.x;
  if (t >= B_ * N_ * 96) return;
  int o = t % 96, bi = t / 96;
  const float* tp = temporal + bi * 64;
  const float* sp = spatial + bi * 64;
  float acc = bf[o];
#pragma unroll
  for (int c = 0; c < 64; c++) {
    acc += tp[c] * WfT[c * 96 + o];
    acc += sp[c] * WfT[(64 + c) * 96 + o];
  }
  xp[t] = acc;
}

// ---------------- GRU scan over node axis: 1 wave per batch ----------------
__global__ __launch_bounds__(64) void gru_kernel(
    const float* __restrict__ xp, const float* __restrict__ Whh,
    const float* __restrict__ bhh, float* __restrict__ hs) {
  int b = blockIdx.x;
  int j = threadIdx.x;        // 0..63: gh[j]; lanes 0..31 also gh[64+j]
  int j2 = 64 + (j & 31);
  float wA[32], wB[32];
#pragma unroll
  for (int i = 0; i < 32; i++) {
    wA[i] = Whh[j * 32 + i];
    wB[i] = Whh[j2 * 32 + i];
  }
  float bA = bhh[j], bB = bhh[j2];
  float h = 0.f;
  const float* xpb = xp + b * N_ * 96;
  for (int n = 0; n < N_; n++) {
    float xA = xpb[n * 96 + j];
    float xB = xpb[n * 96 + 64 + (j & 31)];
    float gA = bA, gB = bB;
#pragma unroll
    for (int i = 0; i < 32; i++) {
      float hi = __shfl(h, i);
      gA += wA[i] * hi;
      gB += wB[i] * hi;
    }
    float xz = __shfl(xA, (j + 32) & 63);
    float hz = __shfl(gA, (j + 32) & 63);
    float r = 1.f / (1.f + __expf(-(xA + gA)));
    float z = 1.f / (1.f + __expf(-(xz + hz)));
    float pre = xB + r * gB;
    float e2 = __expf(2.f * pre);
    float nn = 1.f - 2.f / (e2 + 1.f);  // tanh
    h = (1.f - z) * nn + z * h;          // lanes>=32 hold junk (bounded), never read
    if (j < 32) hs[(b * N_ + n) * HID_ + j] = h;
  }
}

// ---------------- decoder: out = relu(h) @ Wdec.T + bdec ----------------
__global__ __launch_bounds__(256) void decoder_kernel(
    const float* __restrict__ hs, const float* __restrict__ Wdec,
    const float* __restrict__ bdec, float* __restrict__ out) {
  int t = blockIdx.x * 256 + threadIdx.x;
  if (t >= B_ * N_ * OUT_) return;
  int o = t % OUT_, bn = t / OUT_;
  const float* hr = hs + bn * HID_;
  float acc = bdec[o];
#pragma unroll
  for (int k2 = 0; k2 < HID_; k2++) acc += fmaxf(hr[k2], 0.f) * Wdec[o * HID_ + k2];
  out[t] = acc;
}

extern "C" void kernel_launch(void* const* d_in, const int* in_sizes, int n_in,
                              void* d_out, int out_size, void* d_ws, size_t ws_size,
                              hipStream_t stream) {
  const float* x    = (const float*)d_in[0];
  // d_in[1] = adj (unused; edge_index encodes the support)
  const int*   ei   = (const int*)d_in[2];
  const float* ewt  = (const float*)d_in[3];
  const float* Wq   = (const float*)d_in[4];
  const float* bq   = (const float*)d_in[5];
  const float* Wk   = (const float*)d_in[6];
  const float* bk   = (const float*)d_in[7];
  const float* Wd   = (const float*)d_in[8];
  const float* bd   = (const float*)d_in[9];
  const float* c1w0 = (const float*)d_in[10];
  const float* c1b0 = (const float*)d_in[11];
  const float* c2w0 = (const float*)d_in[12];
  const float* c2b0 = (const float*)d_in[13];
  const float* dw0  = (const float*)d_in[14];
  const float* db0  = (const float*)d_in[15];
  const float* c1w1 = (const float*)d_in[16];
  const float* c1b1 = (const float*)d_in[17];
  const float* c2w1 = (const float*)d_in[18];
  const float* c2b1 = (const float*)d_in[19];
  const float* We   = (const float*)d_in[20];
  const float* be   = (const float*)d_in[21];
  const float* Wih  = (const float*)d_in[22];
  const float* Whh  = (const float*)d_in[23];
  const float* bih  = (const float*)d_in[24];
  const float* bhh  = (const float*)d_in[25];
  const float* Wdec = (const float*)d_in[26];
  const float* bdec = (const float*)d_in[27];
  float* out = (float*)d_out;
  float* w = (float*)d_ws;
  const int E = in_sizes[2] / 2;

  float* q    = w + OFF_Q;
  float* k    = w + OFF_K;
  float* mrow = w + OFF_M;
  float* zinv = w + OFF_ZI;
  float* deg  = w + OFF_DEG;
  float* t1o  = w + OFF_T1O;
  float* t1i  = w + OFF_T1I;
  float* spat = w + OFF_SPAT;
  float* temp = w + OFF_TEMP;
  float* WfT  = w + OFF_WFT;
  float* bf   = w + OFF_BF;
  float* xp   = w + OFF_XP;
  float* hs   = w + OFF_HS;

  // zero deg + t1o + t1i (contiguous)
  hipMemsetAsync(deg, 0, (size_t)(2 * N_ + 2 * B_ * N_ * CIN) * sizeof(float), stream);

  wfold_kernel<<<48, 256, 0, stream>>>(We, be, Wih, bih, WfT, bf);
  qk_kernel<<<(B_ * N_ * CIN + 255) / 256, 256, 0, stream>>>(x, Wq, bq, Wk, bk, q, k);
  row_lse_kernel<<<BH_ * 16, 256, 0, stream>>>(q, k, mrow, zinv);
  edge_stats_kernel<<<(E + 255) / 256, 256, 0, stream>>>(q, k, mrow, zinv, ei, ewt, E, deg);
  inv_deg_kernel<<<8, 256, 0, stream>>>(deg);
  scatter_kernel<<<(E * CIN + 255) / 256, 256, 0, stream>>>(x, ei, deg, E, t1o, t1i);
  spatial_kernel<<<(B_ * N_ * EMB_ + 255) / 256, 256, 0, stream>>>(x, t1o, t1i, Wd, bd, spat);
  tcn_kernel<<<B_ * 16, 512, 0, stream>>>(x, c1w0, c1b0, c2w0, c2b0, dw0, db0,
                                          c1w1, c1b1, c2w1, c2b1, temp);
  xp_kernel<<<(B_ * N_ * 96 + 255) / 256, 256, 0, stream>>>(temp, spat, WfT, bf, xp);
  gru_kernel<<<B_, 64, 0, stream>>>(xp, Whh, bhh, hs);
  decoder_kernel<<<(B_ * N_ * OUT_ + 255) / 256, 256, 0, stream>>>(hs, Wdec, bdec, out);
}

// Round 2
// 563.269 us; speedup vs baseline: 2.1406x; 2.1406x over previous
//
#include <hip/hip_runtime.h>
#include <hip/hip_bf16.h>

// Sizes (compile-time)
#define B_ 16
#define N_ 1024
#define CIN 24
#define EMB_ 64
#define HID_ 32
#define OUT_ 12
#define BH_ 32            // B*HEADS
#define RSQRT12 0.28867513459481287f

// ---------------- workspace layout (floats) ----------------
#define OFF_Q      0              // 393216 (reused as t1o after edge_stats)
#define OFF_K      393216         // 393216 (reused as t1i after edge_stats)
#define OFF_M      786432         // 32768
#define OFF_ZI     819200         // 32768
#define OFF_DEG    851968         // 2048 (deg_out[1024], deg_in[1024])
#define OFF_INT    854016         // int area (rp/cp/off/cnt/eids), < 786K floats
#define OFF_SPAT   1640448        // 1048576
#define OFF_TEMP   2689024        // 1048576
#define OFF_WFT    3737600        // 12288  (128 x 96, transposed fold of Wih@We)
#define OFF_BF     3749888        // 128
#define OFF_XP     3750016        // 1572864
#define OFF_HS     5322880        // 524288
// total ~5.85M floats = ~22.3 MB

__device__ __forceinline__ float rdl(float v, int l) {
  return __uint_as_float(__builtin_amdgcn_readlane(__float_as_uint(v), l));
}

// ---------------- q/k projection ----------------
__global__ __launch_bounds__(256) void qk_kernel(
    const float* __restrict__ x, const float* __restrict__ Wq, const float* __restrict__ bq,
    const float* __restrict__ Wk, const float* __restrict__ bk,
    float* __restrict__ q, float* __restrict__ k) {
  int t = blockIdx.x * 256 + threadIdx.x;
  if (t >= B_ * N_ * CIN) return;
  int bi = t / CIN, c = t % CIN;
  int b = bi >> 10, i = bi & (N_ - 1);
  const float* xr = x + bi * CIN;
  float aq = bq[c], ak = bk[c];
#pragma unroll
  for (int d = 0; d < CIN; d++) {
    float xv = xr[d];
    aq += xv * Wq[c * CIN + d];
    ak += xv * Wk[c * CIN + d];
  }
  int h = c / 12, cc = c - h * 12;
  int qi = ((b * 2 + h) * N_ + i) * 12 + cc;
  q[qi] = aq;
  k[qi] = ak;
}

// ---------------- per-row online softmax stats (max, 1/sum) ----------------
__global__ __launch_bounds__(256) void row_lse_kernel(
    const float* __restrict__ q, const float* __restrict__ k,
    float* __restrict__ mrow, float* __restrict__ zinv) {
  __shared__ float ks[N_ * 12];         // 48KB: all K rows for this (b,h)
  __shared__ float pm[4][64];
  __shared__ float pz[4][64];
  int bh = blockIdx.x >> 4;             // 0..31
  int rg = blockIdx.x & 15;             // row group of 64
  const float4* k4 = (const float4*)(k + bh * N_ * 12);
  float4* ks4 = (float4*)ks;
  for (int i = threadIdx.x; i < N_ * 3; i += 256) ks4[i] = k4[i];
  int wave = threadIdx.x >> 6, lane = threadIdx.x & 63;
  int row = rg * 64 + lane;
  float qr[12];
  const float* qp = q + (bh * N_ + row) * 12;
#pragma unroll
  for (int c = 0; c < 12; c++) qr[c] = qp[c];
  __syncthreads();
  float mloc = -1e30f, zloc = 0.f;
  for (int j = wave * 256; j < wave * 256 + 256; j++) {
    const float* kj = ks + j * 12;
    float s = 0.f;
#pragma unroll
    for (int c = 0; c < 12; c++) s += qr[c] * kj[c];
    s *= RSQRT12;
    float mn = fmaxf(mloc, s);
    zloc = zloc * __expf(mloc - mn) + __expf(s - mn);
    mloc = mn;
  }
  pm[wave][lane] = mloc;
  pz[wave][lane] = zloc;
  __syncthreads();
  if (threadIdx.x < 64) {
    int r = rg * 64 + threadIdx.x;
    float M = fmaxf(fmaxf(pm[0][threadIdx.x], pm[1][threadIdx.x]),
                    fmaxf(pm[2][threadIdx.x], pm[3][threadIdx.x]));
    float Z = pz[0][threadIdx.x] * __expf(pm[0][threadIdx.x] - M) +
              pz[1][threadIdx.x] * __expf(pm[1][threadIdx.x] - M) +
              pz[2][threadIdx.x] * __expf(pm[2][threadIdx.x] - M) +
              pz[3][threadIdx.x] * __expf(pm[3][threadIdx.x] - M);
    mrow[bh * N_ + r] = M;
    zinv[bh * N_ + r] = 1.f / Z;
  }
}

// ---------------- per-edge attention score -> ew -> degree atomics ----------------
__global__ __launch_bounds__(256) void edge_stats_kernel(
    const float* __restrict__ q, const float* __restrict__ k,
    const float* __restrict__ mrow, const float* __restrict__ zinv,
    const int* __restrict__ ei, const float* __restrict__ ewt, int E,
    float* __restrict__ deg) {
  int e = blockIdx.x * 256 + threadIdx.x;
  if (e >= E) return;
  int src = ei[e], dst = ei[E + e];
  float acc = 0.f;
  for (int bh = 0; bh < BH_; bh++) {
    const float* qp = q + (bh * N_ + src) * 12;
    const float* kp = k + (bh * N_ + dst) * 12;
    float s = 0.f;
#pragma unroll
    for (int c = 0; c < 12; c++) s += qp[c] * kp[c];
    s *= RSQRT12;
    acc += __expf(s - mrow[bh * N_ + src]) * zinv[bh * N_ + src];
  }
  float w = 25.f * ewt[e] * (acc * (1.f / 32.f));
  atomicAdd(&deg[src], w);
  atomicAdd(&deg[N_ + dst], w);
}

__global__ void inv_deg_kernel(float* deg) {
  int t = blockIdx.x * 256 + threadIdx.x;
  if (t < 2 * N_) deg[t] = 1.f / deg[t];
}

// ---------------- CSR-ish setup: rowptr (src sorted), by-dst grouping ----------------
__global__ void rowptr_kernel(const int* __restrict__ ei, int E, int* __restrict__ rp) {
  int i = blockIdx.x * 256 + threadIdx.x;
  if (i > N_) return;
  int lo = 0, hi = E;
  while (lo < hi) { int mid = (lo + hi) >> 1; if (ei[mid] < i) lo = mid + 1; else hi = mid; }
  rp[i] = lo;
}

__global__ void colcnt_kernel(const int* __restrict__ ei, int E, int* __restrict__ cnt) {
  int e = blockIdx.x * 256 + threadIdx.x;
  if (e < E) atomicAdd(&cnt[ei[E + e]], 1);
}

__global__ __launch_bounds__(1024) void scan_kernel(
    const int* __restrict__ cnt, int* __restrict__ cp, int* __restrict__ off) {
  __shared__ int s[1024];
  int t = threadIdx.x;
  int my = cnt[t];
  s[t] = my;
  __syncthreads();
  for (int d = 1; d < 1024; d <<= 1) {
    int v = (t >= d) ? s[t - d] : 0;
    __syncthreads();
    s[t] += v;
    __syncthreads();
  }
  int excl = s[t] - my;
  cp[t] = excl;
  off[t] = excl;
  if (t == 1023) cp[1024] = s[t];
}

__global__ void colscatter_kernel(const int* __restrict__ ei, int E,
                                  int* __restrict__ off, int* __restrict__ eids) {
  int e = blockIdx.x * 256 + threadIdx.x;
  if (e < E) { int p = atomicAdd(&off[ei[E + e]], 1); eids[p] = e; }
}

// ---------------- atomic-free gathers for t1i / t1o ----------------
// t1i[b,s,c] = sum_{e: src[e]==s} x[b,dst_e,c] * inv_in[dst_e]
__global__ __launch_bounds__(384) void gather_in_kernel(
    const float* __restrict__ x, const int* __restrict__ ei, int E,
    const int* __restrict__ rp, const float* __restrict__ deginv,
    float* __restrict__ t1i) {
  int s = blockIdx.x;
  int e0 = rp[s], e1 = rp[s + 1];
  __shared__ int nd[96];
  __shared__ float wv[96];
  int tid = threadIdx.x;
  int b = tid / 24, c = tid % 24;
  float acc = 0.f;
  for (int base = e0; base < e1; base += 96) {
    int m = min(96, e1 - base);
    if (tid < m) {
      int d = ei[E + base + tid];
      nd[tid] = d;
      wv[tid] = deginv[N_ + d];
    }
    __syncthreads();
    for (int t = 0; t < m; t++) acc += x[(b * N_ + nd[t]) * CIN + c] * wv[t];
    __syncthreads();
  }
  t1i[(b * N_ + s) * CIN + c] = acc;
}

// t1o[b,i,c] = sum_{e: dst[e]==i} x[b,src_e,c] * inv_out[src_e]
__global__ __launch_bounds__(384) void gather_out_kernel(
    const float* __restrict__ x, const int* __restrict__ ei, int E,
    const int* __restrict__ cp, const int* __restrict__ eids,
    const float* __restrict__ deginv, float* __restrict__ t1o) {
  int i = blockIdx.x;
  int e0 = cp[i], e1 = cp[i + 1];
  __shared__ int ns[96];
  __shared__ float wv[96];
  int tid = threadIdx.x;
  int b = tid / 24, c = tid % 24;
  float acc = 0.f;
  for (int base = e0; base < e1; base += 96) {
    int m = min(96, e1 - base);
    if (tid < m) {
      int e = eids[base + tid];
      int sn = ei[e];
      ns[tid] = sn;
      wv[tid] = deginv[sn];
    }
    __syncthreads();
    for (int t = 0; t < m; t++) acc += x[(b * N_ + ns[t]) * CIN + c] * wv[t];
    __syncthreads();
  }
  t1o[(b * N_ + i) * CIN + c] = acc;
}

// ---------------- spatial = relu(x@(W00+W10) + t1o@W01 + t1i@W11 + bd) ----------------
__global__ __launch_bounds__(256) void spatial_kernel(
    const float* __restrict__ x, const float* __restrict__ t1o, const float* __restrict__ t1i,
    const float* __restrict__ Wd, const float* __restrict__ bd, float* __restrict__ sp) {
  int t = blockIdx.x * 256 + threadIdx.x;
  if (t >= B_ * N_ * EMB_) return;
  int o = t & 63, bi = t >> 6;
  const float* xr = x + bi * CIN;
  const float* ar = t1o + bi * CIN;
  const float* br = t1i + bi * CIN;
  float acc = bd[o];
#pragma unroll
  for (int d = 0; d < CIN; d++) {
    acc += xr[d] * (Wd[d * 64 + o] + Wd[3072 + d * 64 + o]);  // Wd[0,0] + Wd[1,0]
    acc += ar[d] * Wd[1536 + d * 64 + o];                     // Wd[0,1]
    acc += br[d] * Wd[4608 + d * 64 + o];                     // Wd[1,1]
  }
  sp[t] = fmaxf(acc, 0.f);
}

// ---------------- fused TCN (2 residual blocks) over node axis ----------------
#define TW 70  // 64 + halo 6
__global__ __launch_bounds__(512) void tcn_kernel(
    const float* __restrict__ x,
    const float* __restrict__ c1w0, const float* __restrict__ c1b0,
    const float* __restrict__ c2w0, const float* __restrict__ c2b0,
    const float* __restrict__ dw0, const float* __restrict__ db0,
    const float* __restrict__ c1w1, const float* __restrict__ c1b1,
    const float* __restrict__ c2w1, const float* __restrict__ c2b1,
    float* __restrict__ temporal) {
  __shared__ float xs[CIN * TW];
  __shared__ float bufA[64 * TW];
  __shared__ float bufB[64 * TW];
  int b = blockIdx.x >> 4;
  int t0 = (blockIdx.x & 15) << 6;
  int tid = threadIdx.x;
  for (int i = tid; i < CIN * TW; i += 512) {
    int ln = i / CIN, c = i % CIN;
    int n = t0 - 6 + ln;
    xs[c * TW + ln] = (n >= 0) ? x[(b * N_ + n) * CIN + c] : 0.f;
  }
  __syncthreads();
  // L1: o1 = relu(conv(x, c1w0, d=1)); mask n<0 to 0 (per-layer causal pad semantics)
  for (int i = tid; i < 64 * (TW - 1); i += 512) {
    int co = i / (TW - 1), ln = 1 + i % (TW - 1);
    const float* w = c1w0 + co * 48;
    float acc = c1b0[co];
#pragma unroll
    for (int ci = 0; ci < CIN; ci++)
      acc += w[ci * 2] * xs[ci * TW + ln - 1] + w[ci * 2 + 1] * xs[ci * TW + ln];
    int n = t0 - 6 + ln;
    bufB[co * TW + ln] = (n >= 0) ? fmaxf(acc, 0.f) : 0.f;
  }
  __syncthreads();
  // L2 + downsample: h1 = relu(relu(conv(o1,c2w0)) + (x@dw0+db0))
  for (int i = tid; i < 64 * (TW - 2); i += 512) {
    int co = i / (TW - 2), ln = 2 + i % (TW - 2);
    const float* w = c2w0 + co * 128;
    float acc = c2b0[co];
#pragma unroll
    for (int ci = 0; ci < 64; ci++)
      acc += w[ci * 2] * bufB[ci * TW + ln - 1] + w[ci * 2 + 1] * bufB[ci * TW + ln];
    const float* wd = dw0 + co * CIN;
    float ds = db0[co];
#pragma unroll
    for (int ci = 0; ci < CIN; ci++) ds += wd[ci] * xs[ci * TW + ln];
    float v = fmaxf(fmaxf(acc, 0.f) + ds, 0.f);
    int n = t0 - 6 + ln;
    bufA[co * TW + ln] = (n >= 0) ? v : 0.f;
  }
  __syncthreads();
  // L3: o3 = relu(conv(h1, c1w1, d=2))
  for (int i = tid; i < 64 * (TW - 4); i += 512) {
    int co = i / (TW - 4), ln = 4 + i % (TW - 4);
    const float* w = c1w1 + co * 128;
    float acc = c1b1[co];
#pragma unroll
    for (int ci = 0; ci < 64; ci++)
      acc += w[ci * 2] * bufA[ci * TW + ln - 2] + w[ci * 2 + 1] * bufA[ci * TW + ln];
    int n = t0 - 6 + ln;
    bufB[co * TW + ln] = (n >= 0) ? fmaxf(acc, 0.f) : 0.f;
  }
  __syncthreads();
  // L4 + residual: out = relu(relu(conv(o3,c2w1,d=2)) + h1); ln in [6,70)
  for (int i = tid; i < 64 * 64; i += 512) {
    int co = i >> 6, ln = 6 + (i & 63);
    const float* w = c2w1 + co * 128;
    float acc = c2b1[co];
#pragma unroll
    for (int ci = 0; ci < 64; ci++)
      acc += w[ci * 2] * bufB[ci * TW + ln - 2] + w[ci * 2 + 1] * bufB[ci * TW + ln];
    float v = fmaxf(fmaxf(acc, 0.f) + bufA[co * TW + ln], 0.f);
    temporal[(b * N_ + t0 + ln - 6) * 64 + co] = v;
  }
}

// ---------------- fold Wih@We (and bias) ----------------
__global__ void wfold_kernel(const float* __restrict__ We, const float* __restrict__ be,
                             const float* __restrict__ Wih, const float* __restrict__ bih,
                             float* __restrict__ WfT, float* __restrict__ bf) {
  int t = blockIdx.x * 256 + threadIdx.x;
  if (t < 128 * 96) {
    int o = t % 96, c = t / 96;
    float acc = 0.f;
#pragma unroll
    for (int e = 0; e < 12; e++) acc += Wih[o * 12 + e] * We[e * 128 + c];
    WfT[c * 96 + o] = acc;  // transposed: [c][o]
  }
  if (t < 96) {
    float acc = bih[t];
#pragma unroll
    for (int e = 0; e < 12; e++) acc += Wih[t * 12 + e] * be[e];
    bf[t] = acc;
  }
}

// ---------------- xp = [temporal|spatial] @ WfT + bf ----------------
__global__ __launch_bounds__(256) void xp_kernel(
    const float* __restrict__ temporal, const float* __restrict__ spatial,
    const float* __restrict__ WfT, const float* __restrict__ bf, float* __restrict__ xp) {
  int t = blockIdx.x * 256 + threadIdx.x;
  if (t >= B_ * N_ * 96) return;
  int o = t % 96, bi = t / 96;
  const float* tp = temporal + bi * 64;
  const float* sp = spatial + bi * 64;
  float acc = bf[o];
#pragma unroll
  for (int c = 0; c < 64; c++) {
    acc += tp[c] * WfT[c * 96 + o];
    acc += sp[c] * WfT[(64 + c) * 96 + o];
  }
  xp[t] = acc;
}

// ---------------- GRU scan: wave0 computes, waves 1-3 double-buffer xp in LDS ----------------
#define CHUNK 64
__global__ __launch_bounds__(256) void gru_kernel(
    const float* __restrict__ xp, const float* __restrict__ Whh,
    const float* __restrict__ bhh, float* __restrict__ hs) {
  __shared__ float4 xbuf4[2][CHUNK * 24];   // 2 x 6144 floats = 48 KB
  int b = blockIdx.x;
  int tid = threadIdx.x;
  int wave = tid >> 6, j = tid & 63;
  const float* xpb = xp + b * N_ * 96;
  // stage chunk 0 (all threads)
  {
    const float4* s4 = (const float4*)xpb;
    for (int i = tid; i < CHUNK * 24; i += 256) xbuf4[0][i] = s4[i];
  }
  float wA[32], wB[32], bA = 0.f, bB = 0.f, h = 0.f;
  if (wave == 0) {
    int j2 = 64 + (j & 31);
#pragma unroll
    for (int i = 0; i < 32; i++) { wA[i] = Whh[j * 32 + i]; wB[i] = Whh[j2 * 32 + i]; }
    bA = bhh[j]; bB = bhh[j2];
  }
  __syncthreads();
  for (int c = 0; c < N_ / CHUNK; c++) {
    if (wave > 0) {
      if (c + 1 < N_ / CHUNK) {
        const float4* s4 = (const float4*)(xpb + (c + 1) * CHUNK * 96);
        float4* d4 = xbuf4[(c + 1) & 1];
        for (int i = tid - 64; i < CHUNK * 24; i += 192) d4[i] = s4[i];
      }
    } else {
      const float* buf = (const float*)xbuf4[c & 1];
      float xA = buf[j], xB = buf[64 + (j & 31)];
      float* hout = hs + (b * N_ + c * CHUNK) * HID_;
      for (int ln = 0; ln < CHUNK; ln++) {
        float nxA = 0.f, nxB = 0.f;
        if (ln + 1 < CHUNK) {
          nxA = buf[(ln + 1) * 96 + j];
          nxB = buf[(ln + 1) * 96 + 64 + (j & 31)];
        }
        float gA0 = bA, gA1 = 0.f, gA2 = 0.f, gA3 = 0.f;
        float gB0 = bB, gB1 = 0.f, gB2 = 0.f, gB3 = 0.f;
#pragma unroll
        for (int i = 0; i < 32; i += 4) {
          float h0 = rdl(h, i), h1 = rdl(h, i + 1), h2 = rdl(h, i + 2), h3 = rdl(h, i + 3);
          gA0 += wA[i] * h0;     gB0 += wB[i] * h0;
          gA1 += wA[i + 1] * h1; gB1 += wB[i + 1] * h1;
          gA2 += wA[i + 2] * h2; gB2 += wB[i + 2] * h2;
          gA3 += wA[i + 3] * h3; gB3 += wB[i + 3] * h3;
        }
        float gA = (gA0 + gA1) + (gA2 + gA3);
        float gB = (gB0 + gB1) + (gB2 + gB3);
        float xz = __shfl_xor(xA, 32, 64);
        float hz = __shfl_xor(gA, 32, 64);
        float r = 1.f / (1.f + __expf(-(xA + gA)));
        float z = 1.f / (1.f + __expf(-(xz + hz)));
        float pre = xB + r * gB;
        float e2 = __expf(2.f * pre);
        float nn = 1.f - 2.f / (e2 + 1.f);  // tanh
        h = (1.f - z) * nn + z * h;          // lanes>=32: bounded junk, never read
        if (j < 32) hout[ln * HID_ + j] = h;
        xA = nxA; xB = nxB;
      }
    }
    __syncthreads();
  }
}

// ---------------- decoder: out = relu(h) @ Wdec.T + bdec ----------------
__global__ __launch_bounds__(256) void decoder_kernel(
    const float* __restrict__ hs, const float* __restrict__ Wdec,
    const float* __restrict__ bdec, float* __restrict__ out) {
  int t = blockIdx.x * 256 + threadIdx.x;
  if (t >= B_ * N_ * OUT_) return;
  int o = t % OUT_, bn = t / OUT_;
  const float* hr = hs + bn * HID_;
  float acc = bdec[o];
#pragma unroll
  for (int k2 = 0; k2 < HID_; k2++) acc += fmaxf(hr[k2], 0.f) * Wdec[o * HID_ + k2];
  out[t] = acc;
}

extern "C" void kernel_launch(void* const* d_in, const int* in_sizes, int n_in,
                              void* d_out, int out_size, void* d_ws, size_t ws_size,
                              hipStream_t stream) {
  const float* x    = (const float*)d_in[0];
  const int*   ei   = (const int*)d_in[2];
  const float* ewt  = (const float*)d_in[3];
  const float* Wq   = (const float*)d_in[4];
  const float* bq   = (const float*)d_in[5];
  const float* Wk   = (const float*)d_in[6];
  const float* bk   = (const float*)d_in[7];
  const float* Wd   = (const float*)d_in[8];
  const float* bd   = (const float*)d_in[9];
  const float* c1w0 = (const float*)d_in[10];
  const float* c1b0 = (const float*)d_in[11];
  const float* c2w0 = (const float*)d_in[12];
  const float* c2b0 = (const float*)d_in[13];
  const float* dw0  = (const float*)d_in[14];
  const float* db0  = (const float*)d_in[15];
  const float* c1w1 = (const float*)d_in[16];
  const float* c1b1 = (const float*)d_in[17];
  const float* c2w1 = (const float*)d_in[18];
  const float* c2b1 = (const float*)d_in[19];
  const float* We   = (const float*)d_in[20];
  const float* be   = (const float*)d_in[21];
  const float* Wih  = (const float*)d_in[22];
  const float* Whh  = (const float*)d_in[23];
  const float* bih  = (const float*)d_in[24];
  const float* bhh  = (const float*)d_in[25];
  const float* Wdec = (const float*)d_in[26];
  const float* bdec = (const float*)d_in[27];
  float* out = (float*)d_out;
  float* w = (float*)d_ws;
  const int E = in_sizes[2] / 2;

  float* q    = w + OFF_Q;
  float* k    = w + OFF_K;
  float* mrow = w + OFF_M;
  float* zinv = w + OFF_ZI;
  float* deg  = w + OFF_DEG;
  float* t1o  = w + OFF_Q;   // reuse after edge_stats
  float* t1i  = w + OFF_K;   // reuse after edge_stats
  float* spat = w + OFF_SPAT;
  float* temp = w + OFF_TEMP;
  float* WfT  = w + OFF_WFT;
  float* bf   = w + OFF_BF;
  float* xp   = w + OFF_XP;
  float* hs   = w + OFF_HS;
  int* ib   = (int*)(w + OFF_INT);
  int* rp   = ib;            // 1025
  int* cp   = ib + 1028;     // 1025
  int* off  = ib + 2056;     // 1024
  int* cnt  = ib + 3084;     // 1024
  int* eids = ib + 4108;     // E

  hipMemsetAsync(deg, 0, (size_t)(2 * N_) * sizeof(float), stream);
  hipMemsetAsync(cnt, 0, (size_t)N_ * sizeof(int), stream);

  // graph structure prep (independent of x)
  rowptr_kernel<<<5, 256, 0, stream>>>(ei, E, rp);
  colcnt_kernel<<<(E + 255) / 256, 256, 0, stream>>>(ei, E, cnt);
  scan_kernel<<<1, 1024, 0, stream>>>(cnt, cp, off);
  colscatter_kernel<<<(E + 255) / 256, 256, 0, stream>>>(ei, E, off, eids);

  wfold_kernel<<<48, 256, 0, stream>>>(We, be, Wih, bih, WfT, bf);
  qk_kernel<<<(B_ * N_ * CIN + 255) / 256, 256, 0, stream>>>(x, Wq, bq, Wk, bk, q, k);
  row_lse_kernel<<<BH_ * 16, 256, 0, stream>>>(q, k, mrow, zinv);
  edge_stats_kernel<<<(E + 255) / 256, 256, 0, stream>>>(q, k, mrow, zinv, ei, ewt, E, deg);
  inv_deg_kernel<<<8, 256, 0, stream>>>(deg);
  // q/k regions now dead -> reused as t1o/t1i
  gather_in_kernel<<<N_, 384, 0, stream>>>(x, ei, E, rp, deg, t1i);
  gather_out_kernel<<<N_, 384, 0, stream>>>(x, ei, E, cp, eids, deg, t1o);
  spatial_kernel<<<(B_ * N_ * EMB_ + 255) / 256, 256, 0, stream>>>(x, t1o, t1i, Wd, bd, spat);
  tcn_kernel<<<B_ * 16, 512, 0, stream>>>(x, c1w0, c1b0, c2w0, c2b0, dw0, db0,
                                          c1w1, c1b1, c2w1, c2b1, temp);
  xp_kernel<<<(B_ * N_ * 96 + 255) / 256, 256, 0, stream>>>(temp, spat, WfT, bf, xp);
  gru_kernel<<<B_, 256, 0, stream>>>(xp, Whh, bhh, hs);
  decoder_kernel<<<(B_ * N_ * OUT_ + 255) / 256, 256, 0, stream>>>(hs, Wdec, bdec, out);
}

// Round 3
// 541.803 us; speedup vs baseline: 2.2254x; 1.0396x over previous
//
#include <hip/hip_runtime.h>
#include <hip/hip_bf16.h>

// Sizes (compile-time)
#define B_ 16
#define N_ 1024
#define CIN 24
#define EMB_ 64
#define HID_ 32
#define OUT_ 12
#define BH_ 32            // B*HEADS
#define RSQRT12 0.28867513459481287f
#define L2E 1.4426950408889634f

// ---------------- workspace layout (floats) ----------------
#define OFF_Q      0              // 393216 (reused as t1o after edge_stats)
#define OFF_K      393216         // 393216 (reused as t1i after edge_stats)
#define OFF_M      786432         // 32768
#define OFF_ZI     819200         // 32768
#define OFF_DEG    851968         // 2048 (deg_out[1024], deg_in[1024])
#define OFF_INT    854016         // int area (rp/cp/off/cnt/eids)
#define OFF_SPAT   1640448        // 1048576
#define OFF_TEMP   2689024        // 1048576
#define OFF_WFT    3737600        // 12288  (128 x 96, transposed fold of Wih@We, prescaled)
#define OFF_BF     3749888        // 128
#define OFF_XP     3750016        // 1572864

__device__ __forceinline__ float rdl(float v, int l) {
  return __uint_as_float(__builtin_amdgcn_readlane(__float_as_uint(v), l));
}

// ---------------- q/k projection ----------------
__global__ __launch_bounds__(256) void qk_kernel(
    const float* __restrict__ x, const float* __restrict__ Wq, const float* __restrict__ bq,
    const float* __restrict__ Wk, const float* __restrict__ bk,
    float* __restrict__ q, float* __restrict__ k) {
  int t = blockIdx.x * 256 + threadIdx.x;
  if (t >= B_ * N_ * CIN) return;
  int bi = t / CIN, c = t % CIN;
  int b = bi >> 10, i = bi & (N_ - 1);
  const float* xr = x + bi * CIN;
  float aq = bq[c], ak = bk[c];
#pragma unroll
  for (int d = 0; d < CIN; d++) {
    float xv = xr[d];
    aq += xv * Wq[c * CIN + d];
    ak += xv * Wk[c * CIN + d];
  }
  int h = c / 12, cc = c - h * 12;
  int qi = ((b * 2 + h) * N_ + i) * 12 + cc;
  q[qi] = aq;
  k[qi] = ak;
}

// ---------------- per-row online softmax stats (max, 1/sum) ----------------
__global__ __launch_bounds__(256) void row_lse_kernel(
    const float* __restrict__ q, const float* __restrict__ k,
    float* __restrict__ mrow, float* __restrict__ zinv) {
  __shared__ float ks[N_ * 12];         // 48KB: all K rows for this (b,h)
  __shared__ float pm[4][64];
  __shared__ float pz[4][64];
  int bh = blockIdx.x >> 4;             // 0..31
  int rg = blockIdx.x & 15;             // row group of 64
  const float4* k4 = (const float4*)(k + bh * N_ * 12);
  float4* ks4 = (float4*)ks;
  for (int i = threadIdx.x; i < N_ * 3; i += 256) ks4[i] = k4[i];
  int wave = threadIdx.x >> 6, lane = threadIdx.x & 63;
  int row = rg * 64 + lane;
  float qr[12];
  const float* qp = q + (bh * N_ + row) * 12;
#pragma unroll
  for (int c = 0; c < 12; c++) qr[c] = qp[c];
  __syncthreads();
  float mloc = -1e30f, zloc = 0.f;
  for (int j = wave * 256; j < wave * 256 + 256; j++) {
    const float* kj = ks + j * 12;
    float s = 0.f;
#pragma unroll
    for (int c = 0; c < 12; c++) s += qr[c] * kj[c];
    s *= RSQRT12;
    float mn = fmaxf(mloc, s);
    zloc = zloc * __expf(mloc - mn) + __expf(s - mn);
    mloc = mn;
  }
  pm[wave][lane] = mloc;
  pz[wave][lane] = zloc;
  __syncthreads();
  if (threadIdx.x < 64) {
    int r = rg * 64 + threadIdx.x;
    float M = fmaxf(fmaxf(pm[0][threadIdx.x], pm[1][threadIdx.x]),
                    fmaxf(pm[2][threadIdx.x], pm[3][threadIdx.x]));
    float Z = pz[0][threadIdx.x] * __expf(pm[0][threadIdx.x] - M) +
              pz[1][threadIdx.x] * __expf(pm[1][threadIdx.x] - M) +
              pz[2][threadIdx.x] * __expf(pm[2][threadIdx.x] - M) +
              pz[3][threadIdx.x] * __expf(pm[3][threadIdx.x] - M);
    mrow[bh * N_ + r] = M;
    zinv[bh * N_ + r] = 1.f / Z;
  }
}

// ---------------- per-edge attention score -> ew -> degree atomics ----------------
__global__ __launch_bounds__(256) void edge_stats_kernel(
    const float* __restrict__ q, const float* __restrict__ k,
    const float* __restrict__ mrow, const float* __restrict__ zinv,
    const int* __restrict__ ei, const float* __restrict__ ewt, int E,
    float* __restrict__ deg) {
  int e = blockIdx.x * 256 + threadIdx.x;
  if (e >= E) return;
  int src = ei[e], dst = ei[E + e];
  float acc = 0.f;
  for (int bh = 0; bh < BH_; bh++) {
    const float* qp = q + (bh * N_ + src) * 12;
    const float* kp = k + (bh * N_ + dst) * 12;
    float s = 0.f;
#pragma unroll
    for (int c = 0; c < 12; c++) s += qp[c] * kp[c];
    s *= RSQRT12;
    acc += __expf(s - mrow[bh * N_ + src]) * zinv[bh * N_ + src];
  }
  float w = 25.f * ewt[e] * (acc * (1.f / 32.f));
  atomicAdd(&deg[src], w);
  atomicAdd(&deg[N_ + dst], w);
}

// ---------------- CSR-ish setup: rowptr (src sorted), by-dst grouping ----------------
__global__ void rowptr_kernel(const int* __restrict__ ei, int E, int* __restrict__ rp) {
  int i = blockIdx.x * 256 + threadIdx.x;
  if (i > N_) return;
  int lo = 0, hi = E;
  while (lo < hi) { int mid = (lo + hi) >> 1; if (ei[mid] < i) lo = mid + 1; else hi = mid; }
  rp[i] = lo;
}

__global__ void colcnt_kernel(const int* __restrict__ ei, int E, int* __restrict__ cnt) {
  int e = blockIdx.x * 256 + threadIdx.x;
  if (e < E) atomicAdd(&cnt[ei[E + e]], 1);
}

__global__ __launch_bounds__(1024) void scan_kernel(
    const int* __restrict__ cnt, int* __restrict__ cp, int* __restrict__ off) {
  __shared__ int s[1024];
  int t = threadIdx.x;
  int my = cnt[t];
  s[t] = my;
  __syncthreads();
  for (int d = 1; d < 1024; d <<= 1) {
    int v = (t >= d) ? s[t - d] : 0;
    __syncthreads();
    s[t] += v;
    __syncthreads();
  }
  int excl = s[t] - my;
  cp[t] = excl;
  off[t] = excl;
  if (t == 1023) cp[1024] = s[t];
}

__global__ void colscatter_kernel(const int* __restrict__ ei, int E,
                                  int* __restrict__ off, int* __restrict__ eids) {
  int e = blockIdx.x * 256 + threadIdx.x;
  if (e < E) { int p = atomicAdd(&off[ei[E + e]], 1); eids[p] = e; }
}

// ---------------- atomic-free gathers for t1i / t1o (rcp of deg folded in) ----------------
__global__ __launch_bounds__(384) void gather_in_kernel(
    const float* __restrict__ x, const int* __restrict__ ei, int E,
    const int* __restrict__ rp, const float* __restrict__ deg,
    float* __restrict__ t1i) {
  int s = blockIdx.x;
  int e0 = rp[s], e1 = rp[s + 1];
  __shared__ int nd[96];
  __shared__ float wv[96];
  int tid = threadIdx.x;
  int b = tid / 24, c = tid % 24;
  float acc = 0.f;
  for (int base = e0; base < e1; base += 96) {
    int m = min(96, e1 - base);
    if (tid < m) {
      int d = ei[E + base + tid];
      nd[tid] = d;
      wv[tid] = __builtin_amdgcn_rcpf(deg[N_ + d]);
    }
    __syncthreads();
    for (int t = 0; t < m; t++) acc += x[(b * N_ + nd[t]) * CIN + c] * wv[t];
    __syncthreads();
  }
  t1i[(b * N_ + s) * CIN + c] = acc;
}

__global__ __launch_bounds__(384) void gather_out_kernel(
    const float* __restrict__ x, const int* __restrict__ ei, int E,
    const int* __restrict__ cp, const int* __restrict__ eids,
    const float* __restrict__ deg, float* __restrict__ t1o) {
  int i = blockIdx.x;
  int e0 = cp[i], e1 = cp[i + 1];
  __shared__ int ns[96];
  __shared__ float wv[96];
  int tid = threadIdx.x;
  int b = tid / 24, c = tid % 24;
  float acc = 0.f;
  for (int base = e0; base < e1; base += 96) {
    int m = min(96, e1 - base);
    if (tid < m) {
      int e = eids[base + tid];
      int sn = ei[e];
      ns[tid] = sn;
      wv[tid] = __builtin_amdgcn_rcpf(deg[sn]);
    }
    __syncthreads();
    for (int t = 0; t < m; t++) acc += x[(b * N_ + ns[t]) * CIN + c] * wv[t];
    __syncthreads();
  }
  t1o[(b * N_ + i) * CIN + c] = acc;
}

// ---------------- spatial = relu(x@(W00+W10) + t1o@W01 + t1i@W11 + bd) ----------------
__global__ __launch_bounds__(256) void spatial_kernel(
    const float* __restrict__ x, const float* __restrict__ t1o, const float* __restrict__ t1i,
    const float* __restrict__ Wd, const float* __restrict__ bd, float* __restrict__ sp) {
  int t = blockIdx.x * 256 + threadIdx.x;
  if (t >= B_ * N_ * EMB_) return;
  int o = t & 63, bi = t >> 6;
  const float* xr = x + bi * CIN;
  const float* ar = t1o + bi * CIN;
  const float* br = t1i + bi * CIN;
  float acc = bd[o];
#pragma unroll
  for (int d = 0; d < CIN; d++) {
    acc += xr[d] * (Wd[d * 64 + o] + Wd[3072 + d * 64 + o]);  // Wd[0,0] + Wd[1,0]
    acc += ar[d] * Wd[1536 + d * 64 + o];                     // Wd[0,1]
    acc += br[d] * Wd[4608 + d * 64 + o];                     // Wd[1,1]
  }
  sp[t] = fmaxf(acc, 0.f);
}

// ---------------- fused TCN (2 residual blocks) over node axis ----------------
#define TW 70  // 64 + halo 6
__global__ __launch_bounds__(512) void tcn_kernel(
    const float* __restrict__ x,
    const float* __restrict__ c1w0, const float* __restrict__ c1b0,
    const float* __restrict__ c2w0, const float* __restrict__ c2b0,
    const float* __restrict__ dw0, const float* __restrict__ db0,
    const float* __restrict__ c1w1, const float* __restrict__ c1b1,
    const float* __restrict__ c2w1, const float* __restrict__ c2b1,
    float* __restrict__ temporal) {
  __shared__ float xs[CIN * TW];
  __shared__ float bufA[64 * TW];
  __shared__ float bufB[64 * TW];
  int b = blockIdx.x >> 4;
  int t0 = (blockIdx.x & 15) << 6;
  int tid = threadIdx.x;
  for (int i = tid; i < CIN * TW; i += 512) {
    int ln = i / CIN, c = i % CIN;
    int n = t0 - 6 + ln;
    xs[c * TW + ln] = (n >= 0) ? x[(b * N_ + n) * CIN + c] : 0.f;
  }
  __syncthreads();
  for (int i = tid; i < 64 * (TW - 1); i += 512) {
    int co = i / (TW - 1), ln = 1 + i % (TW - 1);
    const float* w = c1w0 + co * 48;
    float acc = c1b0[co];
#pragma unroll
    for (int ci = 0; ci < CIN; ci++)
      acc += w[ci * 2] * xs[ci * TW + ln - 1] + w[ci * 2 + 1] * xs[ci * TW + ln];
    int n = t0 - 6 + ln;
    bufB[co * TW + ln] = (n >= 0) ? fmaxf(acc, 0.f) : 0.f;
  }
  __syncthreads();
  for (int i = tid; i < 64 * (TW - 2); i += 512) {
    int co = i / (TW - 2), ln = 2 + i % (TW - 2);
    const float* w = c2w0 + co * 128;
    float acc = c2b0[co];
#pragma unroll
    for (int ci = 0; ci < 64; ci++)
      acc += w[ci * 2] * bufB[ci * TW + ln - 1] + w[ci * 2 + 1] * bufB[ci * TW + ln];
    const float* wd = dw0 + co * CIN;
    float ds = db0[co];
#pragma unroll
    for (int ci = 0; ci < CIN; ci++) ds += wd[ci] * xs[ci * TW + ln];
    float v = fmaxf(fmaxf(acc, 0.f) + ds, 0.f);
    int n = t0 - 6 + ln;
    bufA[co * TW + ln] = (n >= 0) ? v : 0.f;
  }
  __syncthreads();
  for (int i = tid; i < 64 * (TW - 4); i += 512) {
    int co = i / (TW - 4), ln = 4 + i % (TW - 4);
    const float* w = c1w1 + co * 128;
    float acc = c1b1[co];
#pragma unroll
    for (int ci = 0; ci < 64; ci++)
      acc += w[ci * 2] * bufA[ci * TW + ln - 2] + w[ci * 2 + 1] * bufA[ci * TW + ln];
    int n = t0 - 6 + ln;
    bufB[co * TW + ln] = (n >= 0) ? fmaxf(acc, 0.f) : 0.f;
  }
  __syncthreads();
  for (int i = tid; i < 64 * 64; i += 512) {
    int co = i >> 6, ln = 6 + (i & 63);
    const float* w = c2w1 + co * 128;
    float acc = c2b1[co];
#pragma unroll
    for (int ci = 0; ci < 64; ci++)
      acc += w[ci * 2] * bufB[ci * TW + ln - 2] + w[ci * 2 + 1] * bufB[ci * TW + ln];
    float v = fmaxf(fmaxf(acc, 0.f) + bufA[co * TW + ln], 0.f);
    temporal[(b * N_ + t0 + ln - 6) * 64 + co] = v;
  }
}

// ---------------- fold Wih@We (and bias), prescaled: r/z rows x log2e, n rows x 2log2e ----------------
__global__ void wfold_kernel(const float* __restrict__ We, const float* __restrict__ be,
                             const float* __restrict__ Wih, const float* __restrict__ bih,
                             float* __restrict__ WfT, float* __restrict__ bf) {
  int t = blockIdx.x * 256 + threadIdx.x;
  if (t < 128 * 96) {
    int o = t % 96, c = t / 96;
    float acc = 0.f;
#pragma unroll
    for (int e = 0; e < 12; e++) acc += Wih[o * 12 + e] * We[e * 128 + c];
    WfT[c * 96 + o] = acc * ((o < 64) ? L2E : 2.f * L2E);
  }
  if (t < 96) {
    float acc = bih[t];
#pragma unroll
    for (int e = 0; e < 12; e++) acc += Wih[t * 12 + e] * be[e];
    bf[t] = acc * ((t < 64) ? L2E : 2.f * L2E);
  }
}

// ---------------- xp = [temporal|spatial] @ WfT + bf (prescaled) ----------------
__global__ __launch_bounds__(256) void xp_kernel(
    const float* __restrict__ temporal, const float* __restrict__ spatial,
    const float* __restrict__ WfT, const float* __restrict__ bf, float* __restrict__ xp) {
  int t = blockIdx.x * 256 + threadIdx.x;
  if (t >= B_ * N_ * 96) return;
  int o = t % 96, bi = t / 96;
  const float* tp = temporal + bi * 64;
  const float* sp = spatial + bi * 64;
  float acc = bf[o];
#pragma unroll
  for (int c = 0; c < 64; c++) {
    acc += tp[c] * WfT[c * 96 + o];
    acc += sp[c] * WfT[(64 + c) * 96 + o];
  }
  xp[t] = acc;
}

// ---------------- GRU scan + fused decoder ----------------
// wave0 computes; waves 1-3 stage xp chunk c+1 AND decode chunk c-1 from LDS hbuf.
#define CHUNK 64
__global__ __launch_bounds__(256) void gru_kernel(
    const float* __restrict__ xp, const float* __restrict__ Whh,
    const float* __restrict__ bhh, const float* __restrict__ Wdec,
    const float* __restrict__ bdec, float* __restrict__ out) {
  __shared__ float xbuf[2][CHUNK * 96];   // 48 KB
  __shared__ float hbuf[2][CHUNK * 32];   // 16 KB
  __shared__ float wdec_s[12 * 32];
  __shared__ float bdec_s[12];
  int b = blockIdx.x, tid = threadIdx.x;
  int wave = tid >> 6, j = tid & 63, jl = j & 31;
  const float* xpb = xp + b * N_ * 96;
  // stage chunk 0 (all threads) + decoder weights (stagers)
  {
    const float4* s4 = (const float4*)xpb;
    float4* d4 = (float4*)xbuf[0];
    for (int i = tid; i < CHUNK * 24; i += 256) d4[i] = s4[i];
    if (tid >= 64) {
      int t64 = tid - 64;
      for (int i = t64; i < 384; i += 192) wdec_s[i] = Wdec[i];
      if (t64 < 12) bdec_s[t64] = bdec[t64];
    }
  }
  float wA[32], wB[32], bA = 0.f, bB = 0.f, h = 0.f;
  if (wave == 0) {
#pragma unroll
    for (int i = 0; i < 32; i++) {
      wA[i] = L2E * Whh[j * 32 + i];                 // rows j: r (j<32) / z (j>=32)
      wB[i] = 2.f * L2E * Whh[(64 + jl) * 32 + i];   // n rows (dup both halves)
    }
    bA = L2E * bhh[j];
    bB = 2.f * L2E * bhh[64 + jl];
  }
  __syncthreads();
  for (int c = 0; c < 16; c++) {
    if (wave == 0) {
      const float* buf = xbuf[c & 1];
      float* hb = hbuf[c & 1];
      for (int ln = 0; ln < CHUNK; ln++) {
        float xr = buf[ln * 96 + jl];
        float xz = buf[ln * 96 + 32 + jl];
        float xn = buf[ln * 96 + 64 + jl];
        float gA0 = bA, gA1 = 0.f, gA2 = 0.f, gA3 = 0.f;
        float gB0 = bB, gB1 = 0.f, gB2 = 0.f, gB3 = 0.f;
#pragma unroll
        for (int i = 0; i < 32; i += 4) {
          float h0 = rdl(h, i), h1 = rdl(h, i + 1), h2 = rdl(h, i + 2), h3 = rdl(h, i + 3);
          gA0 += wA[i] * h0;     gB0 += wB[i] * h0;
          gA1 += wA[i + 1] * h1; gB1 += wB[i + 1] * h1;
          gA2 += wA[i + 2] * h2; gB2 += wB[i + 2] * h2;
          gA3 += wA[i + 3] * h3; gB3 += wB[i + 3] * h3;
        }
        float gA = (gA0 + gA1) + (gA2 + gA3);   // low: r-dot, high: z-dot (x log2e)
        float gB = (gB0 + gB1) + (gB2 + gB3);   // n-dot (x 2log2e)
        float hz = __shfl_xor(gA, 32);          // z-dot to low lanes; latency hidden below
        float r = __builtin_amdgcn_rcpf(1.f + exp2f(-(xr + gA)));
        float pre = fmaf(r, gB, xn);
        float t = exp2f(pre);
        float nn = fmaf(-2.f, __builtin_amdgcn_rcpf(t + 1.f), 1.f);  // tanh
        float z = __builtin_amdgcn_rcpf(1.f + exp2f(-(xz + hz)));
        h = fmaf(z, h - nn, nn);                // lanes>=32: bounded junk, never read
        if (j < 32) hb[ln * 32 + j] = h;
      }
    } else {
      int t64 = tid - 64;
      if (c + 1 < 16) {
        const float4* s4 = (const float4*)(xpb + (c + 1) * CHUNK * 96);
        float4* d4 = (float4*)xbuf[(c + 1) & 1];
        for (int i = t64; i < CHUNK * 24; i += 192) d4[i] = s4[i];
      }
      if (c > 0) {
        const float* hb = hbuf[(c - 1) & 1];
        int n0 = (c - 1) * CHUNK;
#pragma unroll
        for (int q = 0; q < 4; q++) {
          int idx = q * 192 + t64;
          int nl = idx / 12, o = idx - nl * 12;
          const float4* h4 = (const float4*)(hb + nl * 32);
          const float4* w4 = (const float4*)(wdec_s + o * 32);
          float acc = bdec_s[o];
#pragma unroll
          for (int i = 0; i < 8; i++) {
            float4 hv = h4[i], wv = w4[i];
            acc += fmaxf(hv.x, 0.f) * wv.x + fmaxf(hv.y, 0.f) * wv.y +
                   fmaxf(hv.z, 0.f) * wv.z + fmaxf(hv.w, 0.f) * wv.w;
          }
          out[(b * N_ + n0 + nl) * 12 + o] = acc;
        }
      }
    }
    __syncthreads();
  }
  // decode last chunk (all 256 threads, 3 outputs each)
  {
    const float* hb = hbuf[1];   // chunk 15
    int n0 = 15 * CHUNK;
#pragma unroll
    for (int q = 0; q < 3; q++) {
      int idx = q * 256 + tid;
      int nl = idx / 12, o = idx - nl * 12;
      const float4* h4 = (const float4*)(hb + nl * 32);
      const float4* w4 = (const float4*)(wdec_s + o * 32);
      float acc = bdec_s[o];
#pragma unroll
      for (int i = 0; i < 8; i++) {
        float4 hv = h4[i], wv = w4[i];
        acc += fmaxf(hv.x, 0.f) * wv.x + fmaxf(hv.y, 0.f) * wv.y +
               fmaxf(hv.z, 0.f) * wv.z + fmaxf(hv.w, 0.f) * wv.w;
      }
      out[(b * N_ + n0 + nl) * 12 + o] = acc;
    }
  }
}

extern "C" void kernel_launch(void* const* d_in, const int* in_sizes, int n_in,
                              void* d_out, int out_size, void* d_ws, size_t ws_size,
                              hipStream_t stream) {
  const float* x    = (const float*)d_in[0];
  const int*   ei   = (const int*)d_in[2];
  const float* ewt  = (const float*)d_in[3];
  const float* Wq   = (const float*)d_in[4];
  const float* bq   = (const float*)d_in[5];
  const float* Wk   = (const float*)d_in[6];
  const float* bk   = (const float*)d_in[7];
  const float* Wd   = (const float*)d_in[8];
  const float* bd   = (const float*)d_in[9];
  const float* c1w0 = (const float*)d_in[10];
  const float* c1b0 = (const float*)d_in[11];
  const float* c2w0 = (const float*)d_in[12];
  const float* c2b0 = (const float*)d_in[13];
  const float* dw0  = (const float*)d_in[14];
  const float* db0  = (const float*)d_in[15];
  const float* c1w1 = (const float*)d_in[16];
  const float* c1b1 = (const float*)d_in[17];
  const float* c2w1 = (const float*)d_in[18];
  const float* c2b1 = (const float*)d_in[19];
  const float* We   = (const float*)d_in[20];
  const float* be   = (const float*)d_in[21];
  const float* Wih  = (const float*)d_in[22];
  const float* Whh  = (const float*)d_in[23];
  const float* bih  = (const float*)d_in[24];
  const float* bhh  = (const float*)d_in[25];
  const float* Wdec = (const float*)d_in[26];
  const float* bdec = (const float*)d_in[27];
  float* out = (float*)d_out;
  float* w = (float*)d_ws;
  const int E = in_sizes[2] / 2;

  float* q    = w + OFF_Q;
  float* k    = w + OFF_K;
  float* mrow = w + OFF_M;
  float* zinv = w + OFF_ZI;
  float* deg  = w + OFF_DEG;
  float* t1o  = w + OFF_Q;   // reuse after edge_stats
  float* t1i  = w + OFF_K;   // reuse after edge_stats
  float* spat = w + OFF_SPAT;
  float* temp = w + OFF_TEMP;
  float* WfT  = w + OFF_WFT;
  float* bf   = w + OFF_BF;
  float* xp   = w + OFF_XP;
  int* ib   = (int*)(w + OFF_INT);
  int* rp   = ib;            // 1025
  int* cp   = ib + 1028;     // 1025
  int* off  = ib + 2056;     // 1024
  int* cnt  = ib + 3084;     // 1024
  int* eids = ib + 4108;     // E

  hipMemsetAsync(deg, 0, (size_t)(2 * N_) * sizeof(float), stream);
  hipMemsetAsync(cnt, 0, (size_t)N_ * sizeof(int), stream);

  // graph structure prep (independent of x)
  rowptr_kernel<<<5, 256, 0, stream>>>(ei, E, rp);
  colcnt_kernel<<<(E + 255) / 256, 256, 0, stream>>>(ei, E, cnt);
  scan_kernel<<<1, 1024, 0, stream>>>(cnt, cp, off);
  colscatter_kernel<<<(E + 255) / 256, 256, 0, stream>>>(ei, E, off, eids);

  wfold_kernel<<<48, 256, 0, stream>>>(We, be, Wih, bih, WfT, bf);
  qk_kernel<<<(B_ * N_ * CIN + 255) / 256, 256, 0, stream>>>(x, Wq, bq, Wk, bk, q, k);
  row_lse_kernel<<<BH_ * 16, 256, 0, stream>>>(q, k, mrow, zinv);
  edge_stats_kernel<<<(E + 255) / 256, 256, 0, stream>>>(q, k, mrow, zinv, ei, ewt, E, deg);
  // q/k regions now dead -> reused as t1o/t1i
  gather_in_kernel<<<N_, 384, 0, stream>>>(x, ei, E, rp, deg, t1i);
  gather_out_kernel<<<N_, 384, 0, stream>>>(x, ei, E, cp, eids, deg, t1o);
  spatial_kernel<<<(B_ * N_ * EMB_ + 255) / 256, 256, 0, stream>>>(x, t1o, t1i, Wd, bd, spat);
  tcn_kernel<<<B_ * 16, 512, 0, stream>>>(x, c1w0, c1b0, c2w0, c2b0, dw0, db0,
                                          c1w1, c1b1, c2w1, c2b1, temp);
  xp_kernel<<<(B_ * N_ * 96 + 255) / 256, 256, 0, stream>>>(temp, spat, WfT, bf, xp);
  gru_kernel<<<B_, 256, 0, stream>>>(xp, Whh, bhh, Wdec, bdec, out);
}

// Round 4
// 482.996 us; speedup vs baseline: 2.4963x; 1.1218x over previous
//
#include <hip/hip_runtime.h>
#include <hip/hip_bf16.h>

// Sizes (compile-time)
#define B_ 16
#define N_ 1024
#define CIN 24
#define EMB_ 64
#define HID_ 32
#define OUT_ 12
#define BH_ 32            // B*HEADS
#define RSQRT12 0.28867513459481287f
#define L2E 1.4426950408889634f

// ---------------- workspace layout (floats) ----------------
#define OFF_Q      0              // 393216 (reused as t1o after edge_stats)
#define OFF_K      393216         // 393216 (reused as t1i after edge_stats)
#define OFF_M      786432         // 32768
#define OFF_ZI     819200         // 32768
#define OFF_DEG    851968         // 2048 (deg_out[1024], deg_in[1024])
#define OFF_INT    854016         // int area (rp/cp/eids)
#define OFF_TEMP   2689024        // 1048576
#define OFF_WFT    3737600        // 12288  (128 x 96, transposed fold of Wih@We, prescaled)
#define OFF_BF     3749888        // 128
#define OFF_XP     3750016        // 1572864

__device__ __forceinline__ float rdl(float v, int l) {
  return __uint_as_float(__builtin_amdgcn_readlane(__float_as_uint(v), l));
}

typedef unsigned uvec2 __attribute__((ext_vector_type(2)));

// ---------------- fused: qk projection (blocks 1..384) + graph prep/wfold (block 0) ----------------
__global__ __launch_bounds__(1024) void qk_prep_kernel(
    const float* __restrict__ x, const float* __restrict__ Wq, const float* __restrict__ bq,
    const float* __restrict__ Wk, const float* __restrict__ bk,
    float* __restrict__ q, float* __restrict__ k,
    const int* __restrict__ ei, int E,
    float* __restrict__ deg, int* __restrict__ rp, int* __restrict__ cp,
    int* __restrict__ eids,
    const float* __restrict__ We, const float* __restrict__ be,
    const float* __restrict__ Wih, const float* __restrict__ bih,
    float* __restrict__ WfT, float* __restrict__ bf) {
  __shared__ int cntL[1024];
  __shared__ int sL[1024];
  __shared__ int offL[1024];
  int tid = threadIdx.x;
  if (blockIdx.x == 0) {
    // ---- graph prep + weight fold, single block ----
    deg[tid] = 0.f; deg[N_ + tid] = 0.f;
    cntL[tid] = 0;
    // rowptr: first edge with src >= tid (src sorted row-major)
    { int lo = 0, hi2 = E;
      while (lo < hi2) { int mid = (lo + hi2) >> 1; if (ei[mid] < tid) lo = mid + 1; else hi2 = mid; }
      rp[tid] = lo; }
    if (tid == 0) rp[N_] = E;
    __syncthreads();
    for (int e = tid; e < E; e += 1024) atomicAdd(&cntL[ei[E + e]], 1);
    __syncthreads();
    int my = cntL[tid];
    sL[tid] = my;
    __syncthreads();
    for (int d = 1; d < 1024; d <<= 1) {
      int v = (tid >= d) ? sL[tid - d] : 0;
      __syncthreads();
      sL[tid] += v;
      __syncthreads();
    }
    int excl = sL[tid] - my;
    cp[tid] = excl;
    offL[tid] = excl;
    if (tid == 1023) cp[1024] = sL[tid];
    __syncthreads();
    for (int e = tid; e < E; e += 1024) {
      int p = atomicAdd(&offL[ei[E + e]], 1);
      eids[p] = e;
    }
    // wfold: WfT[c][o] = (Wih@We)[o][c] * scale
    for (int i = tid; i < 128 * 96; i += 1024) {
      int o = i % 96, c = i / 96;
      float acc = 0.f;
#pragma unroll
      for (int e = 0; e < 12; e++) acc += Wih[o * 12 + e] * We[e * 128 + c];
      WfT[c * 96 + o] = acc * ((o < 64) ? L2E : 2.f * L2E);
    }
    if (tid < 96) {
      float acc = bih[tid];
#pragma unroll
      for (int e = 0; e < 12; e++) acc += Wih[tid * 12 + e] * be[e];
      bf[tid] = acc * ((tid < 64) ? L2E : 2.f * L2E);
    }
  } else {
    int t = (blockIdx.x - 1) * 1024 + tid;   // exactly B*N*CIN = 384*1024
    int bi = t / CIN, c = t % CIN;
    int b = bi >> 10, i = bi & (N_ - 1);
    const float* xr = x + bi * CIN;
    float aq = bq[c], ak = bk[c];
#pragma unroll
    for (int d = 0; d < CIN; d++) {
      float xv = xr[d];
      aq += xv * Wq[c * CIN + d];
      ak += xv * Wk[c * CIN + d];
    }
    int h = c / 12, cc = c - h * 12;
    int qi = ((b * 2 + h) * N_ + i) * 12 + cc;
    q[qi] = aq;
    k[qi] = ak;
  }
}

// ---------------- fused: row softmax stats (blocks 0..511) + TCN (blocks 512..767) ----------------
#define TW 70  // 64 + halo 6
__global__ __launch_bounds__(512) void lse_tcn_kernel(
    const float* __restrict__ q, const float* __restrict__ k,
    float* __restrict__ mrow, float* __restrict__ zinv,
    const float* __restrict__ x,
    const float* __restrict__ c1w0, const float* __restrict__ c1b0,
    const float* __restrict__ c2w0, const float* __restrict__ c2b0,
    const float* __restrict__ dw0, const float* __restrict__ db0,
    const float* __restrict__ c1w1, const float* __restrict__ c1b1,
    const float* __restrict__ c2w1, const float* __restrict__ c2b1,
    float* __restrict__ temporal) {
  __shared__ __align__(16) char smem[53248];
  int tid = threadIdx.x;
  if (blockIdx.x < 512) {
    // ---- row LSE: 8 waves x 128 cols each ----
    float* ks = (float*)smem;                       // 12288 floats
    float (*pm)[64] = (float(*)[64])(smem + 49152); // 8x64
    float (*pz)[64] = (float(*)[64])(smem + 51200); // 8x64
    int bh = blockIdx.x >> 4;
    int rg = blockIdx.x & 15;
    const float4* k4 = (const float4*)(k + bh * N_ * 12);
    float4* ks4 = (float4*)ks;
    for (int i = tid; i < N_ * 3; i += 512) ks4[i] = k4[i];
    int wave = tid >> 6, lane = tid & 63;
    int row = rg * 64 + lane;
    float qr[12];
    const float* qp = q + (bh * N_ + row) * 12;
#pragma unroll
    for (int c = 0; c < 12; c++) qr[c] = qp[c];
    __syncthreads();
    float mloc = -1e30f, zloc = 0.f;
    for (int j = wave * 128; j < wave * 128 + 128; j++) {
      const float* kj = ks + j * 12;
      float s = 0.f;
#pragma unroll
      for (int c = 0; c < 12; c++) s += qr[c] * kj[c];
      s *= RSQRT12;
      float mn = fmaxf(mloc, s);
      zloc = zloc * __expf(mloc - mn) + __expf(s - mn);
      mloc = mn;
    }
    pm[wave][lane] = mloc;
    pz[wave][lane] = zloc;
    __syncthreads();
    if (tid < 64) {
      float M = pm[0][tid];
#pragma unroll
      for (int w2 = 1; w2 < 8; w2++) M = fmaxf(M, pm[w2][tid]);
      float Z = 0.f;
#pragma unroll
      for (int w2 = 0; w2 < 8; w2++) Z += pz[w2][tid] * __expf(pm[w2][tid] - M);
      mrow[bh * N_ + rg * 64 + tid] = M;
      zinv[bh * N_ + rg * 64 + tid] = 1.f / Z;
    }
  } else {
    // ---- TCN tile ----
    float* xs   = (float*)smem;        // 24*70
    float* bufA = xs + CIN * TW;       // 64*70
    float* bufB = bufA + 64 * TW;      // 64*70
    int tb = blockIdx.x - 512;
    int b = tb >> 4;
    int t0 = (tb & 15) << 6;
    for (int i = tid; i < CIN * TW; i += 512) {
      int ln = i / CIN, c = i % CIN;
      int n = t0 - 6 + ln;
      xs[c * TW + ln] = (n >= 0) ? x[(b * N_ + n) * CIN + c] : 0.f;
    }
    __syncthreads();
    for (int i = tid; i < 64 * (TW - 1); i += 512) {
      int co = i / (TW - 1), ln = 1 + i % (TW - 1);
      const float* w = c1w0 + co * 48;
      float acc = c1b0[co];
#pragma unroll
      for (int ci = 0; ci < CIN; ci++)
        acc += w[ci * 2] * xs[ci * TW + ln - 1] + w[ci * 2 + 1] * xs[ci * TW + ln];
      int n = t0 - 6 + ln;
      bufB[co * TW + ln] = (n >= 0) ? fmaxf(acc, 0.f) : 0.f;
    }
    __syncthreads();
    for (int i = tid; i < 64 * (TW - 2); i += 512) {
      int co = i / (TW - 2), ln = 2 + i % (TW - 2);
      const float* w = c2w0 + co * 128;
      float acc = c2b0[co];
#pragma unroll
      for (int ci = 0; ci < 64; ci++)
        acc += w[ci * 2] * bufB[ci * TW + ln - 1] + w[ci * 2 + 1] * bufB[ci * TW + ln];
      const float* wd = dw0 + co * CIN;
      float ds = db0[co];
#pragma unroll
      for (int ci = 0; ci < CIN; ci++) ds += wd[ci] * xs[ci * TW + ln];
      float v = fmaxf(fmaxf(acc, 0.f) + ds, 0.f);
      int n = t0 - 6 + ln;
      bufA[co * TW + ln] = (n >= 0) ? v : 0.f;
    }
    __syncthreads();
    for (int i = tid; i < 64 * (TW - 4); i += 512) {
      int co = i / (TW - 4), ln = 4 + i % (TW - 4);
      const float* w = c1w1 + co * 128;
      float acc = c1b1[co];
#pragma unroll
      for (int ci = 0; ci < 64; ci++)
        acc += w[ci * 2] * bufA[ci * TW + ln - 2] + w[ci * 2 + 1] * bufA[ci * TW + ln];
      int n = t0 - 6 + ln;
      bufB[co * TW + ln] = (n >= 0) ? fmaxf(acc, 0.f) : 0.f;
    }
    __syncthreads();
    for (int i = tid; i < 64 * 64; i += 512) {
      int co = i >> 6, ln = 6 + (i & 63);
      const float* w = c2w1 + co * 128;
      float acc = c2b1[co];
#pragma unroll
      for (int ci = 0; ci < 64; ci++)
        acc += w[ci * 2] * bufB[ci * TW + ln - 2] + w[ci * 2 + 1] * bufB[ci * TW + ln];
      float v = fmaxf(fmaxf(acc, 0.f) + bufA[co * TW + ln], 0.f);
      temporal[(b * N_ + t0 + ln - 6) * 64 + co] = v;
    }
  }
}

// ---------------- edge stats: one (edge, bh) per thread, shuffle-reduce over bh ----------------
__global__ __launch_bounds__(256) void edge_stats_kernel(
    const float* __restrict__ q, const float* __restrict__ k,
    const float* __restrict__ mrow, const float* __restrict__ zinv,
    const int* __restrict__ ei, const float* __restrict__ ewt, int E,
    float* __restrict__ deg) {
  int t = blockIdx.x * 256 + threadIdx.x;
  int e = t >> 5, bh = t & 31;
  if (e >= E) return;
  int src = ei[e], dst = ei[E + e];
  const float4* qp = (const float4*)(q + (bh * N_ + src) * 12);
  const float4* kp = (const float4*)(k + (bh * N_ + dst) * 12);
  float s = 0.f;
#pragma unroll
  for (int c4 = 0; c4 < 3; c4++) {
    float4 qv = qp[c4], kv = kp[c4];
    s += qv.x * kv.x + qv.y * kv.y + qv.z * kv.z + qv.w * kv.w;
  }
  s *= RSQRT12;
  float a = __expf(s - mrow[bh * N_ + src]) * zinv[bh * N_ + src];
  a += __shfl_xor(a, 16);
  a += __shfl_xor(a, 8);
  a += __shfl_xor(a, 4);
  a += __shfl_xor(a, 2);
  a += __shfl_xor(a, 1);
  if (bh == 0) {
    float w = 25.f * ewt[e] * (a * (1.f / 32.f));
    atomicAdd(&deg[src], w);
    atomicAdd(&deg[N_ + dst], w);
  }
}

// ---------------- fused atomic-free gathers for t1i (blocks 0..1023) / t1o (1024..2047) ----------------
__global__ __launch_bounds__(384) void gather_io_kernel(
    const float* __restrict__ x, const int* __restrict__ ei, int E,
    const int* __restrict__ rp, const int* __restrict__ cp, const int* __restrict__ eids,
    const float* __restrict__ deg,
    float* __restrict__ t1i, float* __restrict__ t1o) {
  __shared__ int nb[96];
  __shared__ float wv[96];
  bool isOut = blockIdx.x >= N_;
  int node = isOut ? (blockIdx.x - N_) : blockIdx.x;
  int e0 = isOut ? cp[node] : rp[node];
  int e1 = isOut ? cp[node + 1] : rp[node + 1];
  int tid = threadIdx.x;
  int b = tid / 24, c = tid % 24;
  float acc = 0.f;
  for (int base = e0; base < e1; base += 96) {
    int m = min(96, e1 - base);
    if (tid < m) {
      if (isOut) {
        int e = eids[base + tid];
        int sn = ei[e];
        nb[tid] = sn;
        wv[tid] = __builtin_amdgcn_rcpf(deg[sn]);
      } else {
        int d = ei[E + base + tid];
        nb[tid] = d;
        wv[tid] = __builtin_amdgcn_rcpf(deg[N_ + d]);
      }
    }
    __syncthreads();
    for (int t = 0; t < m; t++) acc += x[(b * N_ + nb[t]) * CIN + c] * wv[t];
    __syncthreads();
  }
  float* dst = isOut ? t1o : t1i;
  dst[(b * N_ + node) * CIN + c] = acc;
}

// ---------------- fused spatial + xp: spat tile in LDS, xp straight out ----------------
__global__ __launch_bounds__(256) void spatxp_kernel(
    const float* __restrict__ x, const float* __restrict__ t1o, const float* __restrict__ t1i,
    const float* __restrict__ Wd, const float* __restrict__ bd,
    const float* __restrict__ temporal,
    const float* __restrict__ WfT, const float* __restrict__ bf,
    float* __restrict__ xp) {
  __shared__ float spat_s[64 * 64];
  int b = blockIdx.x >> 4;
  int n0 = (blockIdx.x & 15) << 6;
  int tid = threadIdx.x;
  // phase 1: spatial for 64 nodes x 64 ch
  for (int idx = tid; idx < 4096; idx += 256) {
    int nl = idx >> 6, o = idx & 63;
    int bi = (b * N_ + n0 + nl);
    const float* xr = x + bi * CIN;
    const float* ar = t1o + bi * CIN;
    const float* br = t1i + bi * CIN;
    float acc = bd[o];
#pragma unroll
    for (int d = 0; d < CIN; d++) {
      acc += xr[d] * (Wd[d * 64 + o] + Wd[3072 + d * 64 + o]);
      acc += ar[d] * Wd[1536 + d * 64 + o];
      acc += br[d] * Wd[4608 + d * 64 + o];
    }
    spat_s[nl * 64 + o] = fmaxf(acc, 0.f);
  }
  __syncthreads();
  // phase 2: xp = [temporal | spat] @ WfT + bf
  for (int idx = tid; idx < 6144; idx += 256) {
    int nl = idx / 96, o = idx - nl * 96;
    const float* tp = temporal + (b * N_ + n0 + nl) * 64;
    const float* sp = spat_s + nl * 64;
    float acc = bf[o];
#pragma unroll
    for (int c = 0; c < 64; c++) {
      acc += tp[c] * WfT[c * 96 + o];
      acc += sp[c] * WfT[(64 + c) * 96 + o];
    }
    xp[(b * N_ + n0 + nl) * 96 + o] = acc;
  }
}

// ---------------- GRU scan + fused decoder ----------------
// wave0 computes (low lanes: r-gate, high lanes: z-gate, n duplicated);
// waves 1-3 stage xp chunk c+1 and decode chunk c-1.
#define CHUNK 64
__global__ __launch_bounds__(256) void gru_kernel(
    const float* __restrict__ xp, const float* __restrict__ Whh,
    const float* __restrict__ bhh, const float* __restrict__ Wdec,
    const float* __restrict__ bdec, float* __restrict__ out) {
  __shared__ float xbuf[2][CHUNK * 96];   // 48 KB
  __shared__ float hbuf[2][CHUNK * 68];   // 34.8 KB (stride 68: bank-spread, float4-aligned)
  __shared__ float wdec_s[12 * 36];       // stride 36
  __shared__ float bdec_s[12];
  int b = blockIdx.x, tid = threadIdx.x;
  int wave = tid >> 6, j = tid & 63, jl = j & 31;
  int hi = j >> 5;
  const float* xpb = xp + b * N_ * 96;
  {
    const float4* s4 = (const float4*)xpb;
    float4* d4 = (float4*)xbuf[0];
    for (int i = tid; i < CHUNK * 24; i += 256) d4[i] = s4[i];
    if (tid >= 64) {
      int t64 = tid - 64;
      if (t64 < 12) bdec_s[t64] = bdec[t64];
      for (int i = t64; i < 384; i += 192) wdec_s[(i >> 5) * 36 + (i & 31)] = Wdec[i];
    }
  }
  float wA[32], wB[32], bA = 0.f, bB = 0.f, h = 0.f;
  int xoff = hi ? (32 + jl) : jl;
  if (wave == 0) {
    int rowA = hi ? (32 + jl) : jl;
#pragma unroll
    for (int i = 0; i < 32; i++) {
      wA[i] = L2E * Whh[rowA * 32 + i];              // r-rows (low) / z-rows (high)
      wB[i] = 2.f * L2E * Whh[(64 + jl) * 32 + i];   // n-rows, duplicated
    }
    bA = L2E * bhh[rowA];
    bB = 2.f * L2E * bhh[64 + jl];
  }
  __syncthreads();
  for (int c = 0; c < 16; c++) {
    if (wave == 0) {
      const float* buf = xbuf[c & 1];
      float* hb = hbuf[c & 1];
      float xga = buf[xoff] + bA;
      float xnv = buf[64 + jl];
      for (int ln = 0; ln < CHUNK; ln++) {
        float nxga = 0.f, nxnv = 0.f;
        if (ln + 1 < CHUNK) {
          nxga = buf[(ln + 1) * 96 + xoff] + bA;
          nxnv = buf[(ln + 1) * 96 + 64 + jl];
        }
        float a0 = xga, a1 = 0.f, a2 = 0.f, a3 = 0.f;
        float b0 = bB, b1 = 0.f, b2 = 0.f, b3 = 0.f;
#pragma unroll
        for (int i = 0; i < 32; i += 4) {
          float h0 = rdl(h, i), h1 = rdl(h, i + 1), h2 = rdl(h, i + 2), h3 = rdl(h, i + 3);
          a0 += wA[i] * h0;     b0 += wB[i] * h0;
          a1 += wA[i + 1] * h1; b1 += wB[i + 1] * h1;
          a2 += wA[i + 2] * h2; b2 += wB[i + 2] * h2;
          a3 += wA[i + 3] * h3; b3 += wB[i + 3] * h3;
        }
        float gA = (a0 + a1) + (a2 + a3);    // full sigmoid arg (x+b+Wh), x log2e
        float gB = (b0 + b1) + (b2 + b3);    // n-dot + bias, x 2log2e
        float sg = __builtin_amdgcn_rcpf(1.f + exp2f(-gA));   // low: r, high: z
#if __has_builtin(__builtin_amdgcn_permlane32_swap)
        uvec2 sw = __builtin_amdgcn_permlane32_swap(__float_as_uint(sg), __float_as_uint(sg), false, false);
        float zv = __uint_as_float(sw.y);    // low lanes: z from high half
#else
        float zv = __shfl_xor(sg, 32);
#endif
        float pre = fmaf(sg, gB, xnv);       // low lanes: 2log2e*(xn + r*hn)
        float t = exp2f(pre);
        float nn = fmaf(-2.f, __builtin_amdgcn_rcpf(t + 1.f), 1.f);  // tanh
        h = fmaf(zv, h - nn, nn);            // lanes>=32: bounded junk, never read
        if (j < 32) hb[ln * 68 + j] = h;
        xga = nxga; xnv = nxnv;
      }
    } else {
      int t64 = tid - 64;
      if (c + 1 < 16) {
        const float4* s4 = (const float4*)(xpb + (c + 1) * CHUNK * 96);
        float4* d4 = (float4*)xbuf[(c + 1) & 1];
        for (int i = t64; i < CHUNK * 24; i += 192) d4[i] = s4[i];
      }
      if (c > 0) {
        const float* hb = hbuf[(c - 1) & 1];
        int n0b = (c - 1) * CHUNK;
#pragma unroll
        for (int qq = 0; qq < 4; qq++) {
          int idx = qq * 192 + t64;
          int nl = idx / 12, o = idx - nl * 12;
          const float4* h4 = (const float4*)(hb + nl * 68);
          const float4* w4 = (const float4*)(wdec_s + o * 36);
          float acc = bdec_s[o];
#pragma unroll
          for (int i = 0; i < 8; i++) {
            float4 hv = h4[i], wv = w4[i];
            acc += fmaxf(hv.x, 0.f) * wv.x + fmaxf(hv.y, 0.f) * wv.y +
                   fmaxf(hv.z, 0.f) * wv.z + fmaxf(hv.w, 0.f) * wv.w;
          }
          out[(b * N_ + n0b + nl) * 12 + o] = acc;
        }
      }
    }
    __syncthreads();
  }
  // decode last chunk (all 256 threads, 3 outputs each)
  {
    const float* hb = hbuf[1];   // chunk 15
    int n0b = 15 * CHUNK;
#pragma unroll
    for (int qq = 0; qq < 3; qq++) {
      int idx = qq * 256 + tid;
      int nl = idx / 12, o = idx - nl * 12;
      const float4* h4 = (const float4*)(hb + nl * 68);
      const float4* w4 = (const float4*)(wdec_s + o * 36);
      float acc = bdec_s[o];
#pragma unroll
      for (int i = 0; i < 8; i++) {
        float4 hv = h4[i], wv = w4[i];
        acc += fmaxf(hv.x, 0.f) * wv.x + fmaxf(hv.y, 0.f) * wv.y +
               fmaxf(hv.z, 0.f) * wv.z + fmaxf(hv.w, 0.f) * wv.w;
      }
      out[(b * N_ + n0b + nl) * 12 + o] = acc;
    }
  }
}

extern "C" void kernel_launch(void* const* d_in, const int* in_sizes, int n_in,
                              void* d_out, int out_size, void* d_ws, size_t ws_size,
                              hipStream_t stream) {
  const float* x    = (const float*)d_in[0];
  const int*   ei   = (const int*)d_in[2];
  const float* ewt  = (const float*)d_in[3];
  const float* Wq   = (const float*)d_in[4];
  const float* bq   = (const float*)d_in[5];
  const float* Wk   = (const float*)d_in[6];
  const float* bk   = (const float*)d_in[7];
  const float* Wd   = (const float*)d_in[8];
  const float* bd   = (const float*)d_in[9];
  const float* c1w0 = (const float*)d_in[10];
  const float* c1b0 = (const float*)d_in[11];
  const float* c2w0 = (const float*)d_in[12];
  const float* c2b0 = (const float*)d_in[13];
  const float* dw0  = (const float*)d_in[14];
  const float* db0  = (const float*)d_in[15];
  const float* c1w1 = (const float*)d_in[16];
  const float* c1b1 = (const float*)d_in[17];
  const float* c2w1 = (const float*)d_in[18];
  const float* c2b1 = (const float*)d_in[19];
  const float* We   = (const float*)d_in[20];
  const float* be   = (const float*)d_in[21];
  const float* Wih  = (const float*)d_in[22];
  const float* Whh  = (const float*)d_in[23];
  const float* bih  = (const float*)d_in[24];
  const float* bhh  = (const float*)d_in[25];
  const float* Wdec = (const float*)d_in[26];
  const float* bdec = (const float*)d_in[27];
  float* out = (float*)d_out;
  float* w = (float*)d_ws;
  const int E = in_sizes[2] / 2;

  float* q    = w + OFF_Q;
  float* k    = w + OFF_K;
  float* mrow = w + OFF_M;
  float* zinv = w + OFF_ZI;
  float* deg  = w + OFF_DEG;
  float* t1o  = w + OFF_Q;   // reuse after edge_stats
  float* t1i  = w + OFF_K;   // reuse after edge_stats
  float* temp = w + OFF_TEMP;
  float* WfT  = w + OFF_WFT;
  float* bf   = w + OFF_BF;
  float* xp   = w + OFF_XP;
  int* ib   = (int*)(w + OFF_INT);
  int* rp   = ib;            // 1025
  int* cp   = ib + 1028;     // 1025
  int* eids = ib + 2056;     // E

  qk_prep_kernel<<<385, 1024, 0, stream>>>(x, Wq, bq, Wk, bk, q, k,
                                           ei, E, deg, rp, cp, eids,
                                           We, be, Wih, bih, WfT, bf);
  lse_tcn_kernel<<<768, 512, 0, stream>>>(q, k, mrow, zinv, x,
                                          c1w0, c1b0, c2w0, c2b0, dw0, db0,
                                          c1w1, c1b1, c2w1, c2b1, temp);
  edge_stats_kernel<<<(E * 32 + 255) / 256, 256, 0, stream>>>(q, k, mrow, zinv, ei, ewt, E, deg);
  gather_io_kernel<<<2 * N_, 384, 0, stream>>>(x, ei, E, rp, cp, eids, deg, t1i, t1o);
  spatxp_kernel<<<B_ * 16, 256, 0, stream>>>(x, t1o, t1i, Wd, bd, temp, WfT, bf, xp);
  gru_kernel<<<B_, 256, 0, stream>>>(xp, Whh, bhh, Wdec, bdec, out);
}